// Round 10
// baseline (577.003 us; speedup 1.0000x reference)
//
#include <hip/hip_runtime.h>
#include <hip/hip_bf16.h>
#include <stdint.h>

#define N_NODES 500000
#define F 128
#define B 20000
#define T 8
#define H1 128
#define H2 64
#define C 32
#define S1 5
#define S2 2

typedef __attribute__((ext_vector_type(8))) short s16x8;
typedef __attribute__((ext_vector_type(4))) float f32x4;
typedef __attribute__((ext_vector_type(2))) float f32x2;

// round-to-nearest-even fp32 -> bf16 (bit-level, deterministic)
__device__ __forceinline__ unsigned short f2bf(float v) {
    unsigned int u = __builtin_bit_cast(unsigned int, v);
    unsigned int r = (u + 0x7fffu + ((u >> 16) & 1u)) >> 16;
    return (unsigned short)r;
}
__device__ __forceinline__ float bf2f(unsigned short u) {
    unsigned int x = ((unsigned int)u) << 16;
    return __builtin_bit_cast(float, x);
}

// ---------------------------------------------------------------------------
// K0: split [w_l0 | w_r0] (128x256 fp32) into bf16 hi/lo, TRANSPOSED to
// [n][k] so MFMA W-fragments (8 contiguous k per lane) are single b128 loads.
// Lives in the d_ws "bits" region (consumed before K2 writes bits).
// ---------------------------------------------------------------------------
__global__ __launch_bounds__(256) void k0_wsplit(
    const float* __restrict__ wl, const float* __restrict__ wr,
    unsigned short* __restrict__ whi, unsigned short* __restrict__ wlo)
{
    int idx = blockIdx.x * 256 + threadIdx.x;     // [n][k], 256*128 total
    if (idx >= 256 * 128) return;
    int n = idx >> 7, k = idx & 127;
    float v = (n < 128) ? wl[(size_t)k * 128 + n] : wr[(size_t)k * 128 + (n - 128)];
    unsigned short h = f2bf(v);
    whi[idx] = h;
    wlo[idx] = f2bf(v - bf2f(h));
}

// ---------------------------------------------------------------------------
// K1: PQ[n] = [ x[n]@w_l0 + b_l0 | x[n]@w_r0 + b_r0 ]  via bf16x3 split-MFMA.
// BM=64 rows/block, 4 waves each owning a 64-col quarter of N=256.
// Whole 64x128 A-slab split into LDS once, ONE barrier, barrier-free MFMA.
// R9 change: OPERANDS SWAPPED — mfma(W_frag, x_frag) yields the transposed
// D so each lane holds x-row=fl and 4 CONSECUTIVE cols (4*fg+j), turning the
// epilogue from 64 scalar stores into 16 float4 stores of full 64B lines.
// Fragment loads are unchanged (W-frag has A-layout: row=l&15 indexes W-col
// via [n][k] storage; x-frag has B-layout: n=l&15 indexes x-row).
// ---------------------------------------------------------------------------
__global__ __launch_bounds__(256) void k1_mfma(
    const float* __restrict__ x,
    const unsigned short* __restrict__ whi,
    const unsigned short* __restrict__ wlo,
    const float* __restrict__ b_l0, const float* __restrict__ b_r0,
    float* __restrict__ PQ)
{
    __shared__ unsigned short Ahi[64][136];   // 128 + 8 pad (rows 272B)
    __shared__ unsigned short Alo[64][136];

    const int tid  = threadIdx.x;
    const int wv   = tid >> 6;               // wave 0..3 -> cols wv*64..+63
    const int lane = tid & 63;
    const int fl   = lane & 15;
    const int fg   = lane >> 4;
    const int m0   = blockIdx.x * 64;

    // ---- split phase: thread (row, 32-col segment) ----
    const int srow = tid >> 2;                // 0..63
    const int sc0  = (tid & 3) * 32;          // 0,32,64,96
    const int rowc = min(m0 + srow, N_NODES - 1);   // clamp for tail block
    const float* xbase = x + (size_t)rowc * F + sc0;

    #pragma unroll
    for (int c = 0; c < 4; ++c) {
        float4 v0 = *(const float4*)(xbase + c * 8);
        float4 v1 = *(const float4*)(xbase + c * 8 + 4);
        float xv[8] = {v0.x, v0.y, v0.z, v0.w, v1.x, v1.y, v1.z, v1.w};
        s16x8 ph, pl;
        #pragma unroll
        for (int j = 0; j < 8; ++j) {
            unsigned short h = f2bf(xv[j]);
            ph[j] = (short)h;
            pl[j] = (short)f2bf(xv[j] - bf2f(h));
        }
        *(s16x8*)&Ahi[srow][sc0 + c * 8] = ph;
        *(s16x8*)&Alo[srow][sc0 + c * 8] = pl;
    }
    __syncthreads();

    f32x4 acc[4][4];
    #pragma unroll
    for (int mf = 0; mf < 4; ++mf)
        #pragma unroll
        for (int nf = 0; nf < 4; ++nf)
            acc[mf][nf] = (f32x4){0.f, 0.f, 0.f, 0.f};

    // ---- barrier-free MFMA phase ----
    #pragma unroll
    for (int ks = 0; ks < 4; ++ks) {
        // W fragments (global, L2-hot 128KB); lane: n = base+fl, k = fg*8..
        s16x8 bh[4], bl[4];
        #pragma unroll
        for (int nf = 0; nf < 4; ++nf) {
            size_t n = (size_t)(wv * 64 + 16 * nf + fl);
            bh[nf] = *(const s16x8*)(whi + n * 128 + ks * 32 + fg * 8);
            bl[nf] = *(const s16x8*)(wlo + n * 128 + ks * 32 + fg * 8);
        }
        // x fragments (LDS); lane: row = 16*mf+fl, k = fg*8..
        s16x8 ah[4], al[4];
        #pragma unroll
        for (int mf = 0; mf < 4; ++mf) {
            ah[mf] = *(const s16x8*)&Ahi[16 * mf + fl][ks * 32 + fg * 8];
            al[mf] = *(const s16x8*)&Alo[16 * mf + fl][ks * 32 + fg * 8];
        }
        // 3-pass MFMA, W as first operand (transposed D): WhXh, WlXh, WhXl
        #pragma unroll
        for (int mf = 0; mf < 4; ++mf)
            #pragma unroll
            for (int nf = 0; nf < 4; ++nf) {
                acc[mf][nf] = __builtin_amdgcn_mfma_f32_16x16x32_bf16(
                    bh[nf], ah[mf], acc[mf][nf], 0, 0, 0);
                acc[mf][nf] = __builtin_amdgcn_mfma_f32_16x16x32_bf16(
                    bl[nf], ah[mf], acc[mf][nf], 0, 0, 0);
                acc[mf][nf] = __builtin_amdgcn_mfma_f32_16x16x32_bf16(
                    bh[nf], al[mf], acc[mf][nf], 0, 0, 0);
            }
    }

    // ---- bias: 4 consecutive cols per (nf); col base = wv*64+16nf+4fg ----
    float4 bias4[4];
    #pragma unroll
    for (int nf = 0; nf < 4; ++nf) {
        int cb = wv * 64 + 16 * nf + 4 * fg;
        bias4[nf] = (cb < 128) ? *(const float4*)(b_l0 + cb)
                               : *(const float4*)(b_r0 + cb - 128);
    }

    // ---- store: lane holds row = m0+16mf+fl, cols cb..cb+3 (float4) ----
    #pragma unroll
    for (int mf = 0; mf < 4; ++mf) {
        int row = m0 + 16 * mf + fl;
        if (row < N_NODES) {
            #pragma unroll
            for (int nf = 0; nf < 4; ++nf) {
                float4 o = make_float4(acc[mf][nf][0] + bias4[nf].x,
                                       acc[mf][nf][1] + bias4[nf].y,
                                       acc[mf][nf][2] + bias4[nf].z,
                                       acc[mf][nf][3] + bias4[nf].w);
                *(float4*)&PQ[(size_t)row * 256 + wv * 64 + 16 * nf + 4 * fg] = o;
            }
        }
    }
}

// ---------------------------------------------------------------------------
// K2: one wave per (b,t). All 21 row-gathers issued up front, then ballots,
// then sparse weight-row walks. (R9: at the random-gather memory ceiling —
// 4.97 TB/s served across L3+HBM; MLP pin was a null, removed.)
// ---------------------------------------------------------------------------
__device__ __forceinline__ void mask_walk(unsigned long long m, int par,
                                          const float* __restrict__ w,
                                          int lane, float& acc)
{
    while (m) {
        int i = __builtin_ctzll(m);
        m &= m - 1;
        acc += w[(size_t)(2 * i + par) * H2 + lane];
    }
}

template <int MODE>
__global__ __launch_bounds__(256) void k2_step(
    const float* __restrict__ x,
    const int* __restrict__ nodes, const int* __restrict__ nbr1,
    const int* __restrict__ nbr2,
    const float* __restrict__ w_l0, const float* __restrict__ b_l0,
    const float* __restrict__ w_r0, const float* __restrict__ b_r0,
    const float* __restrict__ w_l1, const float* __restrict__ b_l1,
    const float* __restrict__ w_r1, const float* __restrict__ b_r1,
    const float* __restrict__ PQ,
    unsigned long long* __restrict__ bits)
{
    const int lane = threadIdx.x & 63;
    const int wv   = threadIdx.x >> 6;
    const int gw   = __builtin_amdgcn_readfirstlane((int)(blockIdx.x * 4 + wv));
    const int b    = gw >> 3;
    const int t    = gw & 7;
    const int c2   = lane * 2;

    if (MODE == 0) {
        const int i_self = nodes[b];
        int i1[S1];
        #pragma unroll
        for (int s = 0; s < S1; s++) i1[s] = nbr1[t * (B * S1) + b * S1 + s];
        int i2[S1 * S2];
        #pragma unroll
        for (int q = 0; q < S1 * S2; q++) i2[q] = nbr2[t * (B * S1 * S2) + b * S1 * S2 + q];

        f32x2 sp = *(const f32x2*)(PQ + (size_t)i_self * 256 + c2);
        f32x2 p1[S1], q1[S1], q2[S1 * S2];
        #pragma unroll
        for (int s = 0; s < S1; s++)
            p1[s] = *(const f32x2*)(PQ + (size_t)i1[s] * 256 + c2);
        #pragma unroll
        for (int s = 0; s < S1; s++)
            q1[s] = *(const f32x2*)(PQ + (size_t)i1[s] * 256 + 128 + c2);
        #pragma unroll
        for (int u = 0; u < S1 * S2; u++)
            q2[u] = *(const f32x2*)(PQ + (size_t)i2[u] * 256 + 128 + c2);

        float qsx = 0.f, qsy = 0.f;
        #pragma unroll
        for (int s = 0; s < S1; s++) { qsx += q1[s].x; qsy += q1[s].y; }
        unsigned long long mLx = __ballot(sp.x + 0.2f * qsx >= 1.0f);
        unsigned long long mLy = __ballot(sp.y + 0.2f * qsy >= 1.0f);
        unsigned long long mRx[S1], mRy[S1];
        #pragma unroll
        for (int r = 0; r < S1; r++) {
            float cx = p1[r].x + 0.5f * (q2[2 * r].x + q2[2 * r + 1].x);
            float cy = p1[r].y + 0.5f * (q2[2 * r].y + q2[2 * r + 1].y);
            mRx[r] = __ballot(cx >= 1.0f);
            mRy[r] = __ballot(cy >= 1.0f);
        }

        float aL0 = 0.f, aL1 = 0.f;
        float aR0 = 0.f, aR1 = 0.f, aR2 = 0.f, aR3 = 0.f;
        mask_walk(mLx, 0, w_l1, lane, aL0);
        mask_walk(mLy, 1, w_l1, lane, aL1);
        mask_walk(mRx[0], 0, w_r1, lane, aR0);
        mask_walk(mRy[0], 1, w_r1, lane, aR1);
        mask_walk(mRx[1], 0, w_r1, lane, aR2);
        mask_walk(mRy[1], 1, w_r1, lane, aR3);
        mask_walk(mRx[2], 0, w_r1, lane, aR0);
        mask_walk(mRy[2], 1, w_r1, lane, aR1);
        mask_walk(mRx[3], 0, w_r1, lane, aR2);
        mask_walk(mRy[3], 1, w_r1, lane, aR3);
        mask_walk(mRx[4], 0, w_r1, lane, aR0);
        mask_walk(mRy[4], 1, w_r1, lane, aR1);

        float cur1 = (aL0 + aL1) + 0.2f * ((aR0 + aR1) + (aR2 + aR3))
                   + b_l1[lane] + b_r1[lane];
        unsigned long long sb = __ballot(cur1 >= 1.0f);
        if (lane == 0) bits[(size_t)b * T + t] = sb;
    } else {
        __shared__ float a_lds[4][F];
        __shared__ float n_lds[4][F];
        const int i_self = nodes[b];
        int i1[S1];
        #pragma unroll
        for (int s = 0; s < S1; s++) i1[s] = nbr1[t * (B * S1) + b * S1 + s];
        int i2[S1 * S2];
        #pragma unroll
        for (int q = 0; q < S1 * S2; q++) i2[q] = nbr2[t * (B * S1 * S2) + b * S1 * S2 + q];

        float accL = 0.f, accR = 0.f;
        const float b0x = b_l0[c2] + b_r0[c2];
        const float b0y = b_l0[c2 + 1] + b_r0[c2 + 1];
        float nsx = 0.f, nsy = 0.f;
        #pragma unroll 1
        for (int r = 1; r < 6; r++) {
            const float* ar = x + (size_t)i1[r - 1] * F;
            float ax = ar[c2], ay = ar[c2 + 1];
            nsx += ax; nsy += ay;
            const float* ch0 = x + (size_t)i2[(r - 1) * 2] * F;
            const float* ch1 = x + (size_t)i2[(r - 1) * 2 + 1] * F;
            float nx = 0.5f * (ch0[c2]     + ch1[c2]);
            float ny = 0.5f * (ch0[c2 + 1] + ch1[c2 + 1]);
            a_lds[wv][c2] = ax; a_lds[wv][c2 + 1] = ay;
            n_lds[wv][c2] = nx; n_lds[wv][c2 + 1] = ny;
            float cx = b0x, cy = b0y;
            #pragma unroll 4
            for (int k = 0; k < F; k++) {
                float ak = a_lds[wv][k], nk = n_lds[wv][k];
                const float* wl = w_l0 + (size_t)k * H1 + c2;
                const float* wr = w_r0 + (size_t)k * H1 + c2;
                cx += ak * wl[0] + nk * wr[0];
                cy += ak * wl[1] + nk * wr[1];
            }
            mask_walk(__ballot(cx >= 1.0f), 0, w_r1, lane, accR);
            mask_walk(__ballot(cy >= 1.0f), 1, w_r1, lane, accR);
        }
        {
            const float* ar = x + (size_t)i_self * F;
            float ax = ar[c2], ay = ar[c2 + 1];
            a_lds[wv][c2] = ax; a_lds[wv][c2 + 1] = ay;
            n_lds[wv][c2] = 0.2f * nsx; n_lds[wv][c2 + 1] = 0.2f * nsy;
            float cx = b0x, cy = b0y;
            #pragma unroll 4
            for (int k = 0; k < F; k++) {
                float ak = a_lds[wv][k], nk = n_lds[wv][k];
                const float* wl = w_l0 + (size_t)k * H1 + c2;
                const float* wr = w_r0 + (size_t)k * H1 + c2;
                cx += ak * wl[0] + nk * wr[0];
                cy += ak * wl[1] + nk * wr[1];
            }
            mask_walk(__ballot(cx >= 1.0f), 0, w_l1, lane, accL);
            mask_walk(__ballot(cy >= 1.0f), 1, w_l1, lane, accL);
        }
        float cur1 = accL + 0.2f * accR + b_l1[lane] + b_r1[lane];
        unsigned long long sb = __ballot(cur1 >= 1.0f);
        if (lane == 0) bits[(size_t)b * T + t] = sb;
    }
}

// ---------------------------------------------------------------------------
// K3: out[b][c] = b_pool[c] + sum over set spike bits of w_pool[(t*64+j)][c]
// ---------------------------------------------------------------------------
__global__ __launch_bounds__(256) void k3_pool(
    const float* __restrict__ w_pool, const float* __restrict__ b_pool,
    const unsigned long long* __restrict__ bits, float* __restrict__ out)
{
    const int tid = threadIdx.x;
    const int c = tid & 31;
    const int g = tid >> 5;
    const int b = blockIdx.x * 8 + g;
    if (b >= B) return;
    float acc = b_pool[c];
    #pragma unroll
    for (int t = 0; t < T; t++) {
        unsigned long long m = bits[(size_t)b * T + t];
        while (m) {
            int j = __builtin_ctzll(m);
            m &= m - 1;
            acc += w_pool[(size_t)(t * H2 + j) * C + c];
        }
    }
    out[(size_t)b * C + c] = acc;
}

extern "C" void kernel_launch(void* const* d_in, const int* in_sizes, int n_in,
                              void* d_out, int out_size, void* d_ws, size_t ws_size,
                              hipStream_t stream)
{
    const float* x      = (const float*)d_in[0];
    const int*   nodes  = (const int*)d_in[1];
    const int*   nbr1   = (const int*)d_in[2];
    const int*   nbr2   = (const int*)d_in[3];
    const float* w_l0   = (const float*)d_in[4];
    const float* b_l0   = (const float*)d_in[5];
    const float* w_r0   = (const float*)d_in[6];
    const float* b_r0   = (const float*)d_in[7];
    const float* w_l1   = (const float*)d_in[8];
    const float* b_l1   = (const float*)d_in[9];
    const float* w_r1   = (const float*)d_in[10];
    const float* b_r1   = (const float*)d_in[11];
    const float* w_pool = (const float*)d_in[12];
    const float* b_pool = (const float*)d_in[13];
    float* out = (float*)d_out;

    const size_t pq_bytes   = (size_t)N_NODES * 256 * sizeof(float);          // 512 MB
    const size_t bits_bytes = (size_t)B * T * sizeof(unsigned long long);     // 1.28 MB
    // whi/wlo (64KB each) overlap the bits region: consumed by k0/k1 before
    // k2 writes bits. Total ws requirement unchanged (pq + bits).

    if (ws_size >= pq_bytes + bits_bytes) {
        float* PQ = (float*)d_ws;
        unsigned short* whi = (unsigned short*)((char*)d_ws + pq_bytes);
        unsigned short* wlo = whi + 256 * 128;
        unsigned long long* bits = (unsigned long long*)((char*)d_ws + pq_bytes);

        k0_wsplit<<<128, 256, 0, stream>>>(w_l0, w_r0, whi, wlo);
        k1_mfma<<<(N_NODES + 63) / 64, 256, 0, stream>>>(x, whi, wlo, b_l0, b_r0, PQ);
        k2_step<0><<<(B * T) / 4, 256, 0, stream>>>(x, nodes, nbr1, nbr2,
            w_l0, b_l0, w_r0, b_r0, w_l1, b_l1, w_r1, b_r1, PQ, bits);
        k3_pool<<<B / 8, 256, 0, stream>>>(w_pool, b_pool, bits, out);
    } else {
        unsigned long long* bits = (unsigned long long*)d_ws;
        k2_step<1><<<(B * T) / 4, 256, 0, stream>>>(x, nodes, nbr1, nbr2,
            w_l0, b_l0, w_r0, b_r0, w_l1, b_l1, w_r1, b_r1, nullptr, bits);
        k3_pool<<<B / 8, 256, 0, stream>>>(w_pool, b_pool, bits, out);
    }
}

// Round 11
// 561.781 us; speedup vs baseline: 1.0271x; 1.0271x over previous
//
#include <hip/hip_runtime.h>
#include <hip/hip_bf16.h>
#include <stdint.h>

#define N_NODES 500000
#define F 128
#define B 20000
#define T 8
#define H1 128
#define H2 64
#define C 32
#define S1 5
#define S2 2

typedef __attribute__((ext_vector_type(8))) short s16x8;
typedef __attribute__((ext_vector_type(4))) float f32x4;
typedef __attribute__((ext_vector_type(2))) float f32x2;

// round-to-nearest-even fp32 -> bf16 (bit-level, deterministic)
__device__ __forceinline__ unsigned short f2bf(float v) {
    unsigned int u = __builtin_bit_cast(unsigned int, v);
    unsigned int r = (u + 0x7fffu + ((u >> 16) & 1u)) >> 16;
    return (unsigned short)r;
}
__device__ __forceinline__ float bf2f(unsigned short u) {
    unsigned int x = ((unsigned int)u) << 16;
    return __builtin_bit_cast(float, x);
}

// ---------------------------------------------------------------------------
// K0: split [w_l0 | w_r0] (128x256 fp32) into bf16 hi/lo, TRANSPOSED to
// [n][k] so MFMA B-fragments (8 contiguous k per lane) are single b128 loads.
// Lives in the d_ws "bits" region (consumed before K2 writes bits).
// ---------------------------------------------------------------------------
__global__ __launch_bounds__(256) void k0_wsplit(
    const float* __restrict__ wl, const float* __restrict__ wr,
    unsigned short* __restrict__ whi, unsigned short* __restrict__ wlo)
{
    int idx = blockIdx.x * 256 + threadIdx.x;     // [n][k], 256*128 total
    if (idx >= 256 * 128) return;
    int n = idx >> 7, k = idx & 127;
    float v = (n < 128) ? wl[(size_t)k * 128 + n] : wr[(size_t)k * 128 + (n - 128)];
    unsigned short h = f2bf(v);
    whi[idx] = h;
    wlo[idx] = f2bf(v - bf2f(h));
}

// ---------------------------------------------------------------------------
// K1: PQ[n] = [ x[n]@w_l0 + b_l0 | x[n]@w_r0 + b_r0 ]  via bf16x3 split-MFMA.
// BM=64 rows/block, 4 waves each owning a 64-col quarter of N=256.
// Whole 64x128 A-slab split into LDS once, ONE barrier, barrier-free MFMA.
// R10: reverted R9's operand swap — segment count per wave is identical in
// both epilogue layouts (256 x 64B), and the swap measured -19us. This is
// the best-measured K1 (R8 config, ~190us vs 122us streaming floor).
// Fragment layouts (m89-verified): A row=l&15, k=8*(l>>4)+j; B (stored
// [n][k]) n=l&15, k=8*(l>>4)+j; D col=l&15, row=4*(l>>4)+j.
// ---------------------------------------------------------------------------
__global__ __launch_bounds__(256) void k1_mfma(
    const float* __restrict__ x,
    const unsigned short* __restrict__ whi,
    const unsigned short* __restrict__ wlo,
    const float* __restrict__ b_l0, const float* __restrict__ b_r0,
    float* __restrict__ PQ)
{
    __shared__ unsigned short Ahi[64][136];   // 128 + 8 pad (rows 272B)
    __shared__ unsigned short Alo[64][136];

    const int tid  = threadIdx.x;
    const int wv   = tid >> 6;               // wave 0..3 -> cols wv*64..+63
    const int lane = tid & 63;
    const int fl   = lane & 15;
    const int fg   = lane >> 4;
    const int m0   = blockIdx.x * 64;

    // ---- split phase: thread (row, 32-col segment) ----
    const int srow = tid >> 2;                // 0..63
    const int sc0  = (tid & 3) * 32;          // 0,32,64,96
    const int rowc = min(m0 + srow, N_NODES - 1);   // clamp for tail block
    const float* xbase = x + (size_t)rowc * F + sc0;

    #pragma unroll
    for (int c = 0; c < 4; ++c) {
        float4 v0 = *(const float4*)(xbase + c * 8);
        float4 v1 = *(const float4*)(xbase + c * 8 + 4);
        float xv[8] = {v0.x, v0.y, v0.z, v0.w, v1.x, v1.y, v1.z, v1.w};
        s16x8 ph, pl;
        #pragma unroll
        for (int j = 0; j < 8; ++j) {
            unsigned short h = f2bf(xv[j]);
            ph[j] = (short)h;
            pl[j] = (short)f2bf(xv[j] - bf2f(h));
        }
        *(s16x8*)&Ahi[srow][sc0 + c * 8] = ph;
        *(s16x8*)&Alo[srow][sc0 + c * 8] = pl;
    }
    __syncthreads();

    // per-nf bias (col = wv*64 + 16*nf + fl, fixed per thread)
    float bias_nf[4];
    #pragma unroll
    for (int nf = 0; nf < 4; ++nf) {
        int cc = wv * 64 + 16 * nf + fl;
        bias_nf[nf] = (cc < 128) ? b_l0[cc] : b_r0[cc - 128];
    }

    f32x4 acc[4][4];
    #pragma unroll
    for (int mf = 0; mf < 4; ++mf)
        #pragma unroll
        for (int nf = 0; nf < 4; ++nf)
            acc[mf][nf] = (f32x4){0.f, 0.f, 0.f, 0.f};

    // ---- barrier-free MFMA phase ----
    #pragma unroll
    for (int ks = 0; ks < 4; ++ks) {
        // B fragments (global, L2-hot 128KB)
        s16x8 bh[4], bl[4];
        #pragma unroll
        for (int nf = 0; nf < 4; ++nf) {
            size_t n = (size_t)(wv * 64 + 16 * nf + fl);
            bh[nf] = *(const s16x8*)(whi + n * 128 + ks * 32 + fg * 8);
            bl[nf] = *(const s16x8*)(wlo + n * 128 + ks * 32 + fg * 8);
        }
        // A fragments (LDS)
        s16x8 ah[4], al[4];
        #pragma unroll
        for (int mf = 0; mf < 4; ++mf) {
            ah[mf] = *(const s16x8*)&Ahi[16 * mf + fl][ks * 32 + fg * 8];
            al[mf] = *(const s16x8*)&Alo[16 * mf + fl][ks * 32 + fg * 8];
        }
        // 3-pass MFMA (HH, HL, LH)
        #pragma unroll
        for (int mf = 0; mf < 4; ++mf)
            #pragma unroll
            for (int nf = 0; nf < 4; ++nf) {
                acc[mf][nf] = __builtin_amdgcn_mfma_f32_16x16x32_bf16(
                    ah[mf], bh[nf], acc[mf][nf], 0, 0, 0);
                acc[mf][nf] = __builtin_amdgcn_mfma_f32_16x16x32_bf16(
                    ah[mf], bl[nf], acc[mf][nf], 0, 0, 0);
                acc[mf][nf] = __builtin_amdgcn_mfma_f32_16x16x32_bf16(
                    al[mf], bh[nf], acc[mf][nf], 0, 0, 0);
            }
    }

    // ---- store: D col=fl (per nf), row = 16*mf + 4*fg + j ----
    #pragma unroll
    for (int mf = 0; mf < 4; ++mf) {
        #pragma unroll
        for (int j = 0; j < 4; ++j) {
            int row = m0 + 16 * mf + 4 * fg + j;
            if (row < N_NODES) {
                #pragma unroll
                for (int nf = 0; nf < 4; ++nf) {
                    int col = wv * 64 + 16 * nf + fl;
                    PQ[(size_t)row * 256 + col] = acc[mf][nf][j] + bias_nf[nf];
                }
            }
        }
    }
}

// ---------------------------------------------------------------------------
// K2: one wave per (b,t). All 21 row-gathers issued up front, then ballots,
// then sparse weight-row walks. At the random-gather memory ceiling:
// 4.97 TB/s served (L3+HBM aggregate), 85% occupancy, both pipes idle,
// R8's MLP-pin experiment was a null (VGPR 24->28, dur unchanged).
// ---------------------------------------------------------------------------
__device__ __forceinline__ void mask_walk(unsigned long long m, int par,
                                          const float* __restrict__ w,
                                          int lane, float& acc)
{
    while (m) {
        int i = __builtin_ctzll(m);
        m &= m - 1;
        acc += w[(size_t)(2 * i + par) * H2 + lane];
    }
}

template <int MODE>
__global__ __launch_bounds__(256) void k2_step(
    const float* __restrict__ x,
    const int* __restrict__ nodes, const int* __restrict__ nbr1,
    const int* __restrict__ nbr2,
    const float* __restrict__ w_l0, const float* __restrict__ b_l0,
    const float* __restrict__ w_r0, const float* __restrict__ b_r0,
    const float* __restrict__ w_l1, const float* __restrict__ b_l1,
    const float* __restrict__ w_r1, const float* __restrict__ b_r1,
    const float* __restrict__ PQ,
    unsigned long long* __restrict__ bits)
{
    const int lane = threadIdx.x & 63;
    const int wv   = threadIdx.x >> 6;
    const int gw   = __builtin_amdgcn_readfirstlane((int)(blockIdx.x * 4 + wv));
    const int b    = gw >> 3;
    const int t    = gw & 7;
    const int c2   = lane * 2;

    if (MODE == 0) {
        const int i_self = nodes[b];
        int i1[S1];
        #pragma unroll
        for (int s = 0; s < S1; s++) i1[s] = nbr1[t * (B * S1) + b * S1 + s];
        int i2[S1 * S2];
        #pragma unroll
        for (int q = 0; q < S1 * S2; q++) i2[q] = nbr2[t * (B * S1 * S2) + b * S1 * S2 + q];

        f32x2 sp = *(const f32x2*)(PQ + (size_t)i_self * 256 + c2);
        f32x2 p1[S1], q1[S1], q2[S1 * S2];
        #pragma unroll
        for (int s = 0; s < S1; s++)
            p1[s] = *(const f32x2*)(PQ + (size_t)i1[s] * 256 + c2);
        #pragma unroll
        for (int s = 0; s < S1; s++)
            q1[s] = *(const f32x2*)(PQ + (size_t)i1[s] * 256 + 128 + c2);
        #pragma unroll
        for (int u = 0; u < S1 * S2; u++)
            q2[u] = *(const f32x2*)(PQ + (size_t)i2[u] * 256 + 128 + c2);

        float qsx = 0.f, qsy = 0.f;
        #pragma unroll
        for (int s = 0; s < S1; s++) { qsx += q1[s].x; qsy += q1[s].y; }
        unsigned long long mLx = __ballot(sp.x + 0.2f * qsx >= 1.0f);
        unsigned long long mLy = __ballot(sp.y + 0.2f * qsy >= 1.0f);
        unsigned long long mRx[S1], mRy[S1];
        #pragma unroll
        for (int r = 0; r < S1; r++) {
            float cx = p1[r].x + 0.5f * (q2[2 * r].x + q2[2 * r + 1].x);
            float cy = p1[r].y + 0.5f * (q2[2 * r].y + q2[2 * r + 1].y);
            mRx[r] = __ballot(cx >= 1.0f);
            mRy[r] = __ballot(cy >= 1.0f);
        }

        float aL0 = 0.f, aL1 = 0.f;
        float aR0 = 0.f, aR1 = 0.f, aR2 = 0.f, aR3 = 0.f;
        mask_walk(mLx, 0, w_l1, lane, aL0);
        mask_walk(mLy, 1, w_l1, lane, aL1);
        mask_walk(mRx[0], 0, w_r1, lane, aR0);
        mask_walk(mRy[0], 1, w_r1, lane, aR1);
        mask_walk(mRx[1], 0, w_r1, lane, aR2);
        mask_walk(mRy[1], 1, w_r1, lane, aR3);
        mask_walk(mRx[2], 0, w_r1, lane, aR0);
        mask_walk(mRy[2], 1, w_r1, lane, aR1);
        mask_walk(mRx[3], 0, w_r1, lane, aR2);
        mask_walk(mRy[3], 1, w_r1, lane, aR3);
        mask_walk(mRx[4], 0, w_r1, lane, aR0);
        mask_walk(mRy[4], 1, w_r1, lane, aR1);

        float cur1 = (aL0 + aL1) + 0.2f * ((aR0 + aR1) + (aR2 + aR3))
                   + b_l1[lane] + b_r1[lane];
        unsigned long long sb = __ballot(cur1 >= 1.0f);
        if (lane == 0) bits[(size_t)b * T + t] = sb;
    } else {
        __shared__ float a_lds[4][F];
        __shared__ float n_lds[4][F];
        const int i_self = nodes[b];
        int i1[S1];
        #pragma unroll
        for (int s = 0; s < S1; s++) i1[s] = nbr1[t * (B * S1) + b * S1 + s];
        int i2[S1 * S2];
        #pragma unroll
        for (int q = 0; q < S1 * S2; q++) i2[q] = nbr2[t * (B * S1 * S2) + b * S1 * S2 + q];

        float accL = 0.f, accR = 0.f;
        const float b0x = b_l0[c2] + b_r0[c2];
        const float b0y = b_l0[c2 + 1] + b_r0[c2 + 1];
        float nsx = 0.f, nsy = 0.f;
        #pragma unroll 1
        for (int r = 1; r < 6; r++) {
            const float* ar = x + (size_t)i1[r - 1] * F;
            float ax = ar[c2], ay = ar[c2 + 1];
            nsx += ax; nsy += ay;
            const float* ch0 = x + (size_t)i2[(r - 1) * 2] * F;
            const float* ch1 = x + (size_t)i2[(r - 1) * 2 + 1] * F;
            float nx = 0.5f * (ch0[c2]     + ch1[c2]);
            float ny = 0.5f * (ch0[c2 + 1] + ch1[c2 + 1]);
            a_lds[wv][c2] = ax; a_lds[wv][c2 + 1] = ay;
            n_lds[wv][c2] = nx; n_lds[wv][c2 + 1] = ny;
            float cx = b0x, cy = b0y;
            #pragma unroll 4
            for (int k = 0; k < F; k++) {
                float ak = a_lds[wv][k], nk = n_lds[wv][k];
                const float* wl = w_l0 + (size_t)k * H1 + c2;
                const float* wr = w_r0 + (size_t)k * H1 + c2;
                cx += ak * wl[0] + nk * wr[0];
                cy += ak * wl[1] + nk * wr[1];
            }
            mask_walk(__ballot(cx >= 1.0f), 0, w_r1, lane, accR);
            mask_walk(__ballot(cy >= 1.0f), 1, w_r1, lane, accR);
        }
        {
            const float* ar = x + (size_t)i_self * F;
            float ax = ar[c2], ay = ar[c2 + 1];
            a_lds[wv][c2] = ax; a_lds[wv][c2 + 1] = ay;
            n_lds[wv][c2] = 0.2f * nsx; n_lds[wv][c2 + 1] = 0.2f * nsy;
            float cx = b0x, cy = b0y;
            #pragma unroll 4
            for (int k = 0; k < F; k++) {
                float ak = a_lds[wv][k], nk = n_lds[wv][k];
                const float* wl = w_l0 + (size_t)k * H1 + c2;
                const float* wr = w_r0 + (size_t)k * H1 + c2;
                cx += ak * wl[0] + nk * wr[0];
                cy += ak * wl[1] + nk * wr[1];
            }
            mask_walk(__ballot(cx >= 1.0f), 0, w_l1, lane, accL);
            mask_walk(__ballot(cy >= 1.0f), 1, w_l1, lane, accL);
        }
        float cur1 = accL + 0.2f * accR + b_l1[lane] + b_r1[lane];
        unsigned long long sb = __ballot(cur1 >= 1.0f);
        if (lane == 0) bits[(size_t)b * T + t] = sb;
    }
}

// ---------------------------------------------------------------------------
// K3: out[b][c] = b_pool[c] + sum over set spike bits of w_pool[(t*64+j)][c]
// ---------------------------------------------------------------------------
__global__ __launch_bounds__(256) void k3_pool(
    const float* __restrict__ w_pool, const float* __restrict__ b_pool,
    const unsigned long long* __restrict__ bits, float* __restrict__ out)
{
    const int tid = threadIdx.x;
    const int c = tid & 31;
    const int g = tid >> 5;
    const int b = blockIdx.x * 8 + g;
    if (b >= B) return;
    float acc = b_pool[c];
    #pragma unroll
    for (int t = 0; t < T; t++) {
        unsigned long long m = bits[(size_t)b * T + t];
        while (m) {
            int j = __builtin_ctzll(m);
            m &= m - 1;
            acc += w_pool[(size_t)(t * H2 + j) * C + c];
        }
    }
    out[(size_t)b * C + c] = acc;
}

extern "C" void kernel_launch(void* const* d_in, const int* in_sizes, int n_in,
                              void* d_out, int out_size, void* d_ws, size_t ws_size,
                              hipStream_t stream)
{
    const float* x      = (const float*)d_in[0];
    const int*   nodes  = (const int*)d_in[1];
    const int*   nbr1   = (const int*)d_in[2];
    const int*   nbr2   = (const int*)d_in[3];
    const float* w_l0   = (const float*)d_in[4];
    const float* b_l0   = (const float*)d_in[5];
    const float* w_r0   = (const float*)d_in[6];
    const float* b_r0   = (const float*)d_in[7];
    const float* w_l1   = (const float*)d_in[8];
    const float* b_l1   = (const float*)d_in[9];
    const float* w_r1   = (const float*)d_in[10];
    const float* b_r1   = (const float*)d_in[11];
    const float* w_pool = (const float*)d_in[12];
    const float* b_pool = (const float*)d_in[13];
    float* out = (float*)d_out;

    const size_t pq_bytes   = (size_t)N_NODES * 256 * sizeof(float);          // 512 MB
    const size_t bits_bytes = (size_t)B * T * sizeof(unsigned long long);     // 1.28 MB
    // whi/wlo (64KB each) overlap the bits region: consumed by k0/k1 before
    // k2 writes bits. Total ws requirement unchanged (pq + bits).

    if (ws_size >= pq_bytes + bits_bytes) {
        float* PQ = (float*)d_ws;
        unsigned short* whi = (unsigned short*)((char*)d_ws + pq_bytes);
        unsigned short* wlo = whi + 256 * 128;
        unsigned long long* bits = (unsigned long long*)((char*)d_ws + pq_bytes);

        k0_wsplit<<<128, 256, 0, stream>>>(w_l0, w_r0, whi, wlo);
        k1_mfma<<<(N_NODES + 63) / 64, 256, 0, stream>>>(x, whi, wlo, b_l0, b_r0, PQ);
        k2_step<0><<<(B * T) / 4, 256, 0, stream>>>(x, nodes, nbr1, nbr2,
            w_l0, b_l0, w_r0, b_r0, w_l1, b_l1, w_r1, b_r1, PQ, bits);
        k3_pool<<<B / 8, 256, 0, stream>>>(w_pool, b_pool, bits, out);
    } else {
        unsigned long long* bits = (unsigned long long*)d_ws;
        k2_step<1><<<(B * T) / 4, 256, 0, stream>>>(x, nodes, nbr1, nbr2,
            w_l0, b_l0, w_r0, b_r0, w_l1, b_l1, w_r1, b_r1, nullptr, bits);
        k3_pool<<<B / 8, 256, 0, stream>>>(w_pool, b_pool, bits, out);
    }
}